// Round 8
// baseline (1008.094 us; speedup 1.0000x reference)
//
#include <hip/hip_runtime.h>
#include <math.h>

using half8 = __attribute__((ext_vector_type(8))) _Float16;
using half4 = __attribute__((ext_vector_type(4))) _Float16;
using f32x4 = __attribute__((ext_vector_type(4))) float;

// ---------------------------------------------------------------------------
// Weight re-tiling (device): w (OIHW fp32) -> Wt fp16 tiles [mt][ktile][g][mi][8].
// ktile order: cc (ci chunks of 128) -> khkw (9) -> sub (cw/32).
// ---------------------------------------------------------------------------
template<int CIN, int KC, int M_, int BM>
__device__ void transform_w_dev(float* lds, const float* __restrict__ w,
                                _Float16* __restrict__ wt, int s, int m0, int tid) {
  constexpr int NT = (KC / 32) * 9;
  const int ci0 = s * 32;
  int vlen = (CIN - ci0) * 9;
  if (vlen > 288) vlen = 288;
  if (vlen < 0) vlen = 0;
  for (int e = tid; e < 32 * 288; e += 256) {
    const int mi = e / 288, o = e - mi * 288;
    float v = 0.f;
    if (o < vlen) v = w[(size_t)(m0 + mi) * (CIN * 9) + (size_t)ci0 * 9 + o];
    lds[mi * 289 + o] = v;
  }
  __syncthreads();
  const int cc = s >> 2, sub = s & 3;
  int ns = (KC - 128 * cc) / 32; if (ns > 4) ns = 4;
  const int mt = m0 / BM;
  const int mb = m0 - mt * BM;
  _Float16* base = wt + (size_t)mt * NT * (BM * 32);
  for (int u = tid; u < 36 * 256; u += 256) {
    const int chunk = u >> 8, within = u & 255;
    const int g = chunk & 3, khkw = chunk >> 2;
    const int mi = within >> 3, i = within & 7;
    const int kt = 36 * cc + khkw * ns + sub;
    const float v = lds[mi * 289 + (8 * g + i) * 9 + khkw];
    base[(size_t)kt * (BM * 32) + g * (BM * 8) + (mb + mi) * 8 + i] = (_Float16)v;
  }
}

// Convert + transpose roi chunk: fp32 (obj, 2048, 49) -> fp16 [obj][pos][ci].
__device__ void convert_tr_dev(_Float16 (*t_s)[136], const float* __restrict__ x,
                               _Float16* __restrict__ xh, int cb, int obj, int tid) {
  const int cbase = cb * 128;
  const float* src = x + (size_t)obj * 2048 * 49 + (size_t)cbase * 49;
  for (int e = tid; e < 128 * 49; e += 256) {
    const int ci = e / 49, pos = e - ci * 49;
    t_s[pos][ci] = (_Float16)src[e];
  }
  __syncthreads();
  _Float16* dst = xh + (size_t)obj * 49 * 2048 + cbase;
  for (int u = tid; u < 49 * 16; u += 256) {
    const int pos = u >> 4, l = u & 15;
    *(half8*)&dst[(size_t)pos * 2048 + l * 8] = *(const half8*)&t_s[pos][l * 8];
  }
}

// ---------------------------------------------------------------------------
// fp32 implicit-GEMM conv (device) + split-K partial output (glob path).
// ---------------------------------------------------------------------------
template<int M_, int CIN, int KH, int KW, int H, int W, int OH, int OW,
         int STRIDE, int PAD, int BATCH, int OUTC, int CO_OFF, bool RELU,
         int TM, int TN, int KSPLIT, bool PARTIAL>
__device__ void conv_gemm_dev(char* shraw, const float* __restrict__ A,
                              const float* __restrict__ X,
                              const float* __restrict__ bias,
                              float* __restrict__ out,
                              int n0, int m0, int kz, int t) {
  constexpr int K   = CIN * KH * KW;
  constexpr int N   = BATCH * OH * OW;
  constexpr int BK  = 16;
  constexpr int BM  = 16 * TM;
  constexpr int BN  = 16 * TN;
  constexpr int KCH = K / KSPLIT;

  float (*a_s)[BM] = (float (*)[BM])shraw;
  float (*b_s)[BN] = (float (*)[BN])(shraw + sizeof(float) * BK * BM);

  const int tx = t & 15;
  const int ty = t >> 4;
  constexpr int AQ    = TM / 4;
  constexpr int TPR_A = 4 / AQ;
  const int am = t / TPR_A;
  const int ak = (t % TPR_A) * (4 * AQ);
  constexpr int BQ = TN / 4;
  const int bk = t & 15;
  const int bn = (t >> 4) * TN;

  float acc[TM][TN];
#pragma unroll
  for (int i = 0; i < TM; i++)
#pragma unroll
    for (int j = 0; j < TN; j++) acc[i][j] = 0.f;

  for (int k0 = kz * KCH; k0 < (kz + 1) * KCH; k0 += BK) {
    float4 av[AQ];
#pragma unroll
    for (int q = 0; q < AQ; q++) {
      av[q] = make_float4(0.f, 0.f, 0.f, 0.f);
      const int kq = k0 + ak + 4 * q;
      if ((m0 + am) < M_ && kq < K)
        av[q] = *reinterpret_cast<const float4*>(&A[(m0 + am) * K + kq]);
    }
    float bv[TN];
#pragma unroll
    for (int q = 0; q < TN; q++) bv[q] = 0.f;
    {
      const int kk = k0 + bk;
      if (kk < K) {
        const int ci = kk / (KH * KW);
        const int r  = kk - ci * (KH * KW);
        const int kh = r / KW;
        const int kw = r - kh * KW;
#pragma unroll
        for (int q = 0; q < TN; q++) {
          const int n = n0 + bn + q;
          if (n < N) {
            const int b   = n / (OH * OW);
            const int pos = n - b * (OH * OW);
            const int oh  = pos / OW;
            const int ow  = pos - oh * OW;
            const int ih  = oh * STRIDE - PAD + kh;
            const int iw  = ow * STRIDE - PAD + kw;
            if (ih >= 0 && ih < H && iw >= 0 && iw < W)
              bv[q] = X[((b * CIN + ci) * H + ih) * W + iw];
          }
        }
      }
    }
    __syncthreads();
#pragma unroll
    for (int q = 0; q < AQ; q++) {
      const int kq = ak + 4 * q;
      a_s[kq + 0][am] = av[q].x;
      a_s[kq + 1][am] = av[q].y;
      a_s[kq + 2][am] = av[q].z;
      a_s[kq + 3][am] = av[q].w;
    }
#pragma unroll
    for (int q = 0; q < BQ; q++)
      *reinterpret_cast<float4*>(&b_s[bk][bn + 4 * q]) =
          make_float4(bv[4 * q], bv[4 * q + 1], bv[4 * q + 2], bv[4 * q + 3]);
    __syncthreads();
#pragma unroll
    for (int kk2 = 0; kk2 < BK; kk2++) {
      float a[TM], b[TN];
#pragma unroll
      for (int q = 0; q < AQ; q++)
        *reinterpret_cast<float4*>(&a[4 * q]) =
            *reinterpret_cast<const float4*>(&a_s[kk2][ty * TM + 4 * q]);
#pragma unroll
      for (int q = 0; q < BQ; q++)
        *reinterpret_cast<float4*>(&b[4 * q]) =
            *reinterpret_cast<const float4*>(&b_s[kk2][tx * TN + 4 * q]);
#pragma unroll
      for (int i = 0; i < TM; i++)
#pragma unroll
        for (int j = 0; j < TN; j++)
          acc[i][j] = fmaf(a[i], b[j], acc[i][j]);
    }
  }

#pragma unroll
  for (int i = 0; i < TM; i++) {
    const int m = m0 + ty * TM + i;
    if (m < M_) {
#pragma unroll
      for (int j = 0; j < TN; j++) {
        const int n = n0 + tx * TN + j;
        if (n < N) {
          if (PARTIAL) {
            out[((size_t)kz * M_ + m) * N + n] = acc[i][j];
          } else {
            float v = acc[i][j] + bias[m];
            if (RELU) v = fmaxf(v, 0.f);
            const int b   = n / (OH * OW);
            const int pos = n - b * (OH * OW);
            out[(b * OUTC + CO_OFF + m) * (OH * OW) + pos] = v;
          }
        }
      }
    }
  }
}

template<int M_, int CIN, int KH, int KW, int H, int W, int OH, int OW,
         int STRIDE, int PAD, int BATCH, int OUTC, int CO_OFF, bool RELU,
         int TM, int TN, int KSPLIT, bool PARTIAL>
__global__ __launch_bounds__(256)
void conv_gemm(const float* __restrict__ A, const float* __restrict__ X,
               const float* __restrict__ bias, float* __restrict__ out) {
  __shared__ char sh[16 * (16 * TM + 16 * TN) * 4];
  conv_gemm_dev<M_, CIN, KH, KW, H, W, OH, OW, STRIDE, PAD, BATCH, OUTC, CO_OFF,
                RELU, TM, TN, KSPLIT, PARTIAL>(
      sh, A, X, bias, out, blockIdx.x * 16 * TN, blockIdx.y * 16 * TM,
      blockIdx.z, threadIdx.x);
}

// ---------------------------------------------------------------------------
// Fused prep kernels (blockIdx dispatch; shared via char union).
// ---------------------------------------------------------------------------
__global__ __launch_bounds__(256)
void prep1(const float* __restrict__ w_obj1, _Float16* __restrict__ wbuf1,
           const float* __restrict__ roi, _Float16* __restrict__ xh1) {
  __shared__ char sh[32 * 289 * 4];
  int b = blockIdx.x;
  if (b < 2048) {
    transform_w_dev<2048, 2048, 1024, 512>((float*)sh, w_obj1, wbuf1,
                                           b & 63, (b >> 6) * 32, threadIdx.x);
  } else {
    b -= 2048;  // 4096 blocks
    convert_tr_dev((_Float16(*)[136])sh, roi, xh1, b & 15, b >> 4, threadIdx.x);
  }
}

__global__ __launch_bounds__(256)
void prep2(const float* __restrict__ w_obj2, _Float16* __restrict__ wbuf2,
           const float* __restrict__ w_sel1, _Float16* __restrict__ wbufs1,
           const float* __restrict__ w_glob1, const float* __restrict__ gfeat,
           float* __restrict__ part1) {
  __shared__ char sh[32 * 289 * 4];
  int b = blockIdx.x;
  if (b < 256) {
    transform_w_dev<1024, 1024, 256, 128>((float*)sh, w_obj2, wbuf2,
                                          b & 31, (b >> 5) * 32, threadIdx.x);
  } else if (b < 392) {
    b -= 256;  // 136 blocks
    transform_w_dev<516, 544, 256, 128>((float*)sh, w_sel1, wbufs1,
                                        b % 17, (b / 17) * 32, threadIdx.x);
  } else {
    b -= 392;  // 512 blocks
    conv_gemm_dev<512, 1024, 4, 4, 28, 28, 14, 14, 2, 1, 1, 512, 0, true,
                  4, 4, 16, true>(sh, w_glob1, gfeat, nullptr, part1,
                                  (b & 3) * 64, ((b >> 2) & 7) * 64, b >> 5,
                                  threadIdx.x);
  }
}

// ---------------------------------------------------------------------------
// obj1 conv: BM=512, 8 waves x WM=64 channels (FR=4), FN=7 fragments covering
// BOTH objects' 98 positions (12.5% pad waste vs 23%). Weight fragments read
// once per block-ktile (no duplication) -> L2 weight traffic halved vs R7.
// Raw barriers (no vmcnt drain), depth-2 weight register pipeline, setprio.
// Epilogue: LDS transpose (ot_s ALIASES x_s) -> coalesced fp16 [pos][ch] rows.
// ---------------------------------------------------------------------------
template<int KC, int BM, int FN, int OHW, int PAD, int NMT, int NOP>
__global__ __launch_bounds__(512)
void conv_mfma2(const _Float16* __restrict__ Wt, const _Float16* __restrict__ X,
                const float* __restrict__ bias, _Float16* __restrict__ out,
                int outc, int co_off) {
  constexpr int NT   = (KC / 32) * 9;
  constexpr int OPOS = OHW * OHW;
  constexpr int WM   = BM / 8;
  constexpr int FR   = WM / 16;
  constexpr int NCH  = KC / 128;   // KC % 128 == 0

  __shared__ alignas(16) _Float16 x_s[2][50][136];

  const int tid  = threadIdx.x;
  const int wid  = tid >> 6;
  const int lane = tid & 63;
  const int g    = lane >> 4;
  const int ln   = lane & 15;
  const int wm   = wid * WM;

  const int bid = blockIdx.x;
  const int j = bid & 7, q = bid >> 3;
  constexpr int OPJ = 8 / NMT;
  const int mt = j / OPJ;
  const int op = (j % OPJ) * (NOP / OPJ) + q;

  if (tid < 272) x_s[tid / 136][49][tid % 136] = (_Float16)0.f;

  int ohv[FN], owv[FN], objv[FN];
  bool pvv[FN];
#pragma unroll
  for (int f = 0; f < FN; f++) {
    const int p = ln + 16 * f;
    pvv[f] = p < 2 * OPOS;
    const int ob = pvv[f] ? (p / OPOS) : 1;
    objv[f] = ob;
    const int pp = pvv[f] ? (p - ob * OPOS) : 0;
    ohv[f] = pp / OHW;
    owv[f] = pp % OHW;
  }

  f32x4 acc[FR][FN];
#pragma unroll
  for (int r = 0; r < FR; r++)
#pragma unroll
    for (int f = 0; f < FN; f++) acc[r][f] = (f32x4){0.f, 0.f, 0.f, 0.f};

  const _Float16* Xh = X + (size_t)(2 * op) * 49 * KC;

  half8 rg[4];
  auto load_chunk = [&](int cbase) {
#pragma unroll
    for (int v = 0; v < 4; v++) {
      const int u = v * 512 + tid;
      if (u < 1568) {
        const int row = u >> 4, l = u & 15;
        const int o = row >= 49 ? 1 : 0, pos = row - 49 * o;
        rg[v] = *(const half8*)(Xh + (size_t)(o * 49 + pos) * KC + cbase + l * 8);
      }
    }
  };
  auto write_chunk = [&]() {
#pragma unroll
    for (int v = 0; v < 4; v++) {
      const int u = v * 512 + tid;
      if (u < 1568) {
        const int row = u >> 4, l = u & 15;
        const int o = row >= 49 ? 1 : 0, pos = row - 49 * o;
        *(half8*)&x_s[o][pos][l * 8] = rg[v];
      }
    }
  };

  // weight register pipeline, depth 2 (3 rotating buffers); final prefetches
  // read <=32KB past this mt tile -- valid ws memory, values never consumed.
  const _Float16* ap = Wt + (size_t)mt * NT * (BM * 32) + (g * BM + wm + ln) * 8;
  half8 afA[FR], afB[FR], afC[FR];
#pragma unroll
  for (int r = 0; r < FR; r++) afA[r] = *(const half8*)(ap + r * 128);
  ap += BM * 32;
#pragma unroll
  for (int r = 0; r < FR; r++) afB[r] = *(const half8*)(ap + r * 128);
  ap += BM * 32;

  load_chunk(0);

  auto kstep = [&](half8 (&cur)[FR], half8 (&fut)[FR], int subbyte,
                   const int (&boff)[FN]) {
#pragma unroll
    for (int r = 0; r < FR; r++) fut[r] = *(const half8*)(ap + r * 128);
    ap += BM * 32;
    __builtin_amdgcn_s_setprio(1);
    const char* xb = (const char*)(&x_s[0][0][0]) + subbyte;
#pragma unroll
    for (int f = 0; f < FN; f++) {
      const half8 bf = *(const half8*)(xb + boff[f]);
#pragma unroll
      for (int r = 0; r < FR; r++)
        acc[r][f] = __builtin_amdgcn_mfma_f32_16x16x32_f16(cur[r], bf, acc[r][f], 0, 0, 0);
    }
    __builtin_amdgcn_s_setprio(0);
  };

  for (int c = 0; c < NCH; c++) {
    asm volatile("s_barrier" ::: "memory");          // x_s reads of c-1 done
    write_chunk();
    if (c + 1 < NCH) load_chunk((c + 1) * 128);      // stays in flight
    asm volatile("s_waitcnt lgkmcnt(0)\n\ts_barrier" ::: "memory");
#pragma unroll
    for (int t9 = 0; t9 < 9; t9++) {
      const int kh = t9 / 3, kw = t9 - 3 * (t9 / 3);
      int boff[FN];
#pragma unroll
      for (int f = 0; f < FN; f++) {
        const int ih = ohv[f] + kh - PAD;
        const int iw = owv[f] + kw - PAD;
        bool v = pvv[f];
        if (PAD) v = v && ((unsigned)ih < 7u) && ((unsigned)iw < 7u);
        const int row = v ? (ih * 7 + iw) : 49;
        boff[f] = (objv[f] * 50 * 136 + row * 136) * 2;
      }
#pragma unroll
      for (int s4 = 0; s4 < 4; s4++) {
        const int ph = (t9 * 4 + s4) % 3;
        const int subbyte = (s4 * 32 + 8 * g) * 2;
        if (ph == 0)      kstep(afA, afC, subbyte, boff);
        else if (ph == 1) kstep(afB, afA, subbyte, boff);
        else              kstep(afC, afB, subbyte, boff);
      }
    }
  }

  // ---- epilogue: fp16 transposed output via LDS (ot_s aliases x_s) ----
  _Float16 (*ot_s)[49][132] = (_Float16 (*)[49][132]) & x_s[0][0][0];
  constexpr int PASSES = BM / 128;
#pragma unroll
  for (int p = 0; p < PASSES; p++) {
    asm volatile("s_waitcnt lgkmcnt(0)\n\ts_barrier" ::: "memory");
    if (wm >= 128 * p && wm < 128 * (p + 1)) {
#pragma unroll
      for (int f = 0; f < FN; f++) {
        if (pvv[f]) {
          const int pos = ohv[f] * OHW + owv[f];
          const int ob  = objv[f];
#pragma unroll
          for (int r = 0; r < FR; r++) {
            const int cl = wm - 128 * p + r * 16 + g * 4;
            half4 h;
#pragma unroll
            for (int e = 0; e < 4; e++)
              h[e] = (_Float16)fmaxf(
                  acc[r][f][e] + bias[mt * BM + wm + r * 16 + g * 4 + e], 0.f);
            *(half4*)&ot_s[ob][pos][cl] = h;
          }
        }
      }
    }
    asm volatile("s_waitcnt lgkmcnt(0)\n\ts_barrier" ::: "memory");
    for (int u = tid; u < 2 * OPOS * 32; u += 512) {
      const int row = u >> 5, l = u & 31;
      const int o = row >= OPOS ? 1 : 0, pos = row - OPOS * o;
      const half4 v = *(const half4*)&ot_s[o][pos][l * 4];
      *(half4*)&out[((size_t)(2 * op + o) * OPOS + pos) * outc + co_off +
                    mt * BM + 128 * p + l * 4] = v;
    }
  }
}

// ---------------------------------------------------------------------------
// R7-style conv (obj2 / sel1): BM=128, obj-paired waves, FN frags per object.
// ot_s aliases x_s; barrier before pass 0 protects the union.
// ---------------------------------------------------------------------------
template<int KC, int BM, int FN, int OHW, int PAD, bool TOUT, typename OUT_T,
         int NMT, int NOP>
__global__ __launch_bounds__(512)
void conv_mfma(const _Float16* __restrict__ Wt, const _Float16* __restrict__ X,
               const float* __restrict__ bias, OUT_T* __restrict__ out,
               int outc, int co_off) {
  constexpr int NT    = (KC / 32) * 9;
  constexpr int OPOS  = OHW * OHW;
  constexpr int WM    = BM / 4;
  constexpr int FR    = WM / 16;
  constexpr int CFULL = KC / 128;
  constexpr int TAIL  = KC - CFULL * 128;
  constexpr int NCH   = CFULL + (TAIL ? 1 : 0);

  __shared__ alignas(16) _Float16 x_s[2][50][136];

  const int tid  = threadIdx.x;
  const int wid  = tid >> 6;
  const int lane = tid & 63;
  const int g    = lane >> 4;
  const int ln   = lane & 15;
  const int obj  = wid >> 2;
  const int wm   = (wid & 3) * WM;

  const int bid = blockIdx.x;
  const int j = bid & 7, q = bid >> 3;
  constexpr int OPJ = 8 / NMT;
  const int mt = j / OPJ;
  const int op = (j % OPJ) * (NOP / OPJ) + q;

  if (tid < 272) x_s[tid / 136][49][tid % 136] = (_Float16)0.f;

  int ohv[FN], owv[FN];
  bool pvv[FN];
#pragma unroll
  for (int f = 0; f < FN; f++) {
    const int pos = ln + 16 * f;
    pvv[f] = pos < OPOS;
    ohv[f] = pos / OHW;
    owv[f] = pos % OHW;
  }

  f32x4 acc[FR][FN];
#pragma unroll
  for (int r = 0; r < FR; r++)
#pragma unroll
    for (int f = 0; f < FN; f++) acc[r][f] = (f32x4){0.f, 0.f, 0.f, 0.f};

  const _Float16* Xh = X + (size_t)(2 * op) * 49 * KC;

  half8 rg[4];
  auto load_chunk = [&](int cbase, int cw) {
    if (cw == 128) {
#pragma unroll
      for (int v = 0; v < 4; v++) {
        const int u = v * 512 + tid;
        if (u < 1568) {
          const int row = u >> 4, l = u & 15;
          const int o = row >= 49 ? 1 : 0, pos = row - 49 * o;
          rg[v] = *(const half8*)(Xh + (size_t)(o * 49 + pos) * KC + cbase + l * 8);
        }
      }
    } else {
      if (tid < 392) {
        const int row = tid >> 2, l = tid & 3;
        const int o = row >= 49 ? 1 : 0, pos = row - 49 * o;
        rg[0] = *(const half8*)(Xh + (size_t)(o * 49 + pos) * KC + cbase + l * 8);
      }
    }
  };
  auto write_chunk = [&](int cw) {
    if (cw == 128) {
#pragma unroll
      for (int v = 0; v < 4; v++) {
        const int u = v * 512 + tid;
        if (u < 1568) {
          const int row = u >> 4, l = u & 15;
          const int o = row >= 49 ? 1 : 0, pos = row - 49 * o;
          *(half8*)&x_s[o][pos][l * 8] = rg[v];
        }
      }
    } else {
      if (tid < 392) {
        const int row = tid >> 2, l = tid & 3;
        const int o = row >= 49 ? 1 : 0, pos = row - 49 * o;
        *(half8*)&x_s[o][pos][l * 8] = rg[0];
      }
    }
  };

  const _Float16* ap = Wt + (size_t)mt * NT * (BM * 32) + (g * BM + wm + ln) * 8;
  half8 afA[FR], afB[FR], afC[FR];
#pragma unroll
  for (int r = 0; r < FR; r++) afA[r] = *(const half8*)(ap + r * 128);
  ap += BM * 32;
#pragma unroll
  for (int r = 0; r < FR; r++) afB[r] = *(const half8*)(ap + r * 128);
  ap += BM * 32;

  load_chunk(0, KC < 128 ? KC : 128);

  auto kstep = [&](half8 (&cur)[FR], half8 (&fut)[FR], int subbyte,
                   const int (&boff)[FN]) {
#pragma unroll
    for (int r = 0; r < FR; r++) fut[r] = *(const half8*)(ap + r * 128);
    ap += BM * 32;
    __builtin_amdgcn_s_setprio(1);
    const char* xb = (const char*)(&x_s[0][0][0]) + subbyte;
#pragma unroll
    for (int f = 0; f < FN; f++) {
      const half8 bf = *(const half8*)(xb + boff[f]);
#pragma unroll
      for (int r = 0; r < FR; r++)
        acc[r][f] = __builtin_amdgcn_mfma_f32_16x16x32_f16(cur[r], bf, acc[r][f], 0, 0, 0);
    }
    __builtin_amdgcn_s_setprio(0);
  };

  int ktile = 0;
  for (int c = 0; c < NCH; c++) {
    const int cw = (c < CFULL) ? 128 : TAIL;
    asm volatile("s_barrier" ::: "memory");
    write_chunk(cw);
    if (c + 1 < NCH)
      load_chunk((c + 1) * 128, (c + 1 < CFULL) ? 128 : TAIL);
    asm volatile("s_waitcnt lgkmcnt(0)\n\ts_barrier" ::: "memory");
    const int nsub = cw / 32;
    for (int khkw = 0; khkw < 9; khkw++) {
      const int kh = khkw / 3, kw = khkw - 3 * (khkw / 3);
      int boff[FN];
#pragma unroll
      for (int f = 0; f < FN; f++) {
        const int ih = ohv[f] + kh - PAD;
        const int iw = owv[f] + kw - PAD;
        bool v = pvv[f];
        if (PAD) v = v && ((unsigned)ih < 7u) && ((unsigned)iw < 7u);
        const int row = v ? (ih * 7 + iw) : 49;
        boff[f] = (obj * 50 * 136 + row * 136) * 2;
      }
      for (int sub = 0; sub < nsub; sub++) {
        const int ph = ktile % 3;
        const int subbyte = (sub * 32 + 8 * g) * 2;
        if (ph == 0)      kstep(afA, afC, subbyte, boff);
        else if (ph == 1) kstep(afB, afA, subbyte, boff);
        else              kstep(afC, afB, subbyte, boff);
        ktile++;
      }
    }
  }

  if constexpr (TOUT) {
    _Float16 (*ot_s)[49][132] = (_Float16 (*)[49][132]) & x_s[0][0][0];
    asm volatile("s_waitcnt lgkmcnt(0)\n\ts_barrier" ::: "memory");
#pragma unroll
    for (int f = 0; f < FN; f++) {
      const int pos = ln + 16 * f;
      if (pos < OPOS) {
#pragma unroll
        for (int r = 0; r < FR; r++) {
          const int cl = wm + r * 16 + g * 4;
          half4 h;
#pragma unroll
          for (int e = 0; e < 4; e++)
            h[e] = (_Float16)fmaxf(
                acc[r][f][e] + bias[mt * BM + wm + r * 16 + g * 4 + e], 0.f);
          *(half4*)&ot_s[obj][pos][cl] = h;
        }
      }
    }
    asm volatile("s_waitcnt lgkmcnt(0)\n\ts_barrier" ::: "memory");
    _Float16* dst = (_Float16*)out;
    for (int u = tid; u < 2 * OPOS * 32; u += 512) {
      const int row = u >> 5, l = u & 31;
      const int o = row >= OPOS ? 1 : 0, pos = row - OPOS * o;
      const half4 v = *(const half4*)&ot_s[o][pos][l * 4];
      *(half4*)&dst[((size_t)(2 * op + o) * OPOS + pos) * outc + co_off +
                    mt * BM + l * 4] = v;
    }
  } else {
    const int bo = 2 * op + obj;
#pragma unroll
    for (int f = 0; f < FN; f++) {
      const int pos = ln + 16 * f;
      if (pos < OPOS) {
#pragma unroll
        for (int r = 0; r < FR; r++) {
          const int mrow = mt * BM + wm + r * 16 + g * 4;
#pragma unroll
          for (int e = 0; e < 4; e++) {
            const int m = mrow + e;
            float v = fmaxf(acc[r][f][e] + bias[m], 0.f);
            out[((size_t)bo * outc + co_off + m) * OPOS + pos] = (OUT_T)v;
          }
        }
      }
    }
  }
}

__global__ void reduce_bias_relu(const float* __restrict__ part,
                                 const float* __restrict__ bias,
                                 float* __restrict__ out, int MN, int N, int KS) {
  const int e = blockIdx.x * 256 + threadIdx.x;
  if (e >= MN) return;
  float s = 0.f;
  for (int k = 0; k < KS; k++) s += part[(size_t)k * MN + e];
  s += bias[e / N];
  out[e] = fmaxf(s, 0.f);
}

// sel2: x = sel1buf f32 (256,256,5,5) NCHW, w (16,256,3,3) -> out (256,16,9).
__global__ __launch_bounds__(256)
void sel2_kernel(const float* __restrict__ x, const float* __restrict__ w,
                 const float* __restrict__ b, float* __restrict__ out) {
  const int wv   = (blockIdx.x * 256 + threadIdx.x) >> 6;
  const int lane = threadIdx.x & 63;
  const int obj  = wv >> 4, co = wv & 15;
  float acc[9];
#pragma unroll
  for (int p = 0; p < 9; p++) acc[p] = 0.f;
  const float* xo = x + (size_t)obj * 256 * 25;
  const float* wo = w + (size_t)co * 2304;
  for (int k = lane; k < 2304; k += 64) {
    const int ci = k / 9, rr = k - 9 * ci;
    const int kh = rr / 3, kw = rr - 3 * kh;
    const float wval = wo[k];
    const float* xc = xo + ci * 25;
#pragma unroll
    for (int oh = 0; oh < 3; oh++)
#pragma unroll
      for (int ow = 0; ow < 3; ow++)
        acc[oh * 3 + ow] = fmaf(xc[(oh + kh) * 5 + (ow + kw)], wval, acc[oh * 3 + ow]);
  }
  const float bv = b[co];
#pragma unroll
  for (int p = 0; p < 9; p++) {
    float v = acc[p];
#pragma unroll
    for (int off = 32; off; off >>= 1) v += __shfl_xor(v, off);
    if (lane == 0) out[(size_t)wv * 9 + p] = fmaxf(v + bv, 0.f);
  }
}

// sin_t buffer (256, 49, 544) fp16: ch 0..3 = bb, 260..515 = glob, 516..543=0.
__global__ void prep_sin_t(const float* __restrict__ bbox,
                           const float* __restrict__ glob,
                           _Float16* __restrict__ sint) {
  const int b = blockIdx.x;
  const float x0 = bbox[b * 4 + 0], y0 = bbox[b * 4 + 1];
  const float x1 = bbox[b * 4 + 2], y1 = bbox[b * 4 + 3];
  const float bbv[4] = {x0 / 1280.f, y0 / 720.f,
                        logf(1280.f / (x1 - x0)), logf(720.f / (y1 - y0))};
  _Float16* base = sint + (size_t)b * 49 * 544;
  for (int e = threadIdx.x; e < 49 * 288; e += blockDim.x) {
    const int pos = e / 288, q = e - pos * 288;
    float v; int c;
    if (q < 4)        { v = bbv[q];                   c = q; }
    else if (q < 260) { v = glob[(q - 4) * 49 + pos]; c = q + 256; }
    else              { v = 0.f;                      c = q + 256; }
    base[pos * 544 + c] = (_Float16)v;
  }
}

// ---------------------------------------------------------------------------
// head: scores (sel3) + stable top-5 + pooling + fc1 + fc2 + fc3, one block.
// ---------------------------------------------------------------------------
__global__ __launch_bounds__(512)
void head_kernel(const float* __restrict__ sel2, const float* __restrict__ w3,
                 const float* __restrict__ b3, const _Float16* __restrict__ sint,
                 const float* __restrict__ glob, const float* __restrict__ w1,
                 const float* __restrict__ b1, const float* __restrict__ w2,
                 const float* __restrict__ b2, const float* __restrict__ wf3,
                 const float* __restrict__ bf3, float* __restrict__ out) {
  __shared__ float w3_s[144];
  __shared__ float s_s[256];
  __shared__ int   idx_s[5];
  __shared__ float objsel_s[5 * 260];
  __shared__ float g_s[256];
  __shared__ float x1_s[1280];
  __shared__ float x2_s[64];
  const int t = threadIdx.x;
  if (t < 144) w3_s[t] = w3[t];
  __syncthreads();
  if (t < 256) {
    float acc = b3[0];
    const float* p = sel2 + t * 144;
    for (int k = 0; k < 144; k++) acc += p[k] * w3_s[k];
    s_s[t] = acc;
  } else {
    const int c = t - 256;
    float s = 0.f;
    const float* p = glob + c * 49;
    for (int q = 0; q < 49; q++) s += p[q];
    g_s[c] = s * (1.f / 49.f);
  }
  __syncthreads();
  if (t == 0) {
    // argsort(-s) stable: strict '>' + ascending scan = smallest index first
    for (int i = 0; i < 5; i++) {
      float best = -1e30f; int bi = 0;
      for (int j = 0; j < 256; j++)
        if (s_s[j] > best) { best = s_s[j]; bi = j; }
      idx_s[i] = bi;
      s_s[bi] = -1e30f;
    }
  }
  __syncthreads();
  for (int e = t; e < 5 * 260; e += 512) {
    const int i = e / 260, c = e - 260 * i;
    const _Float16* base = sint + (size_t)idx_s[i] * 49 * 544;
    float s = 0.f;
    for (int p = 0; p < 49; p++) s += (float)base[p * 544 + c];
    objsel_s[e] = s * (1.f / 245.f);
  }
  __syncthreads();
  if (t < 256) {
    float acc[5];
#pragma unroll
    for (int i = 0; i < 5; i++) acc[i] = b1[t];
    for (int k = 0; k < 260; k++) {
      const float wv = w1[k * 256 + t];
#pragma unroll
      for (int i = 0; i < 5; i++) acc[i] = fmaf(objsel_s[i * 260 + k], wv, acc[i]);
    }
    for (int k = 260; k < 516; k++) {
      const float wv = w1[k * 256 + t];
      const float gv = g_s[k - 260];
#pragma unroll
      for (int i = 0; i < 5; i++) acc[i] = fmaf(gv, wv, acc[i]);
    }
#pragma unroll
    for (int i = 0; i < 5; i++) x1_s[i * 256 + t] = fmaxf(acc[i], 0.f);
  }
  __syncthreads();
  if (t < 64) {
    float a = b2[t];
    for (int k = 0; k < 1280; k++) a = fmaf(x1_s[k], w2[k * 64 + t], a);
    x2_s[t] = fmaxf(a, 0.f);
  }
  __syncthreads();
  if (t < 4) {
    float a = bf3[t];
    for (int k = 0; k < 64; k++) a = fmaf(x2_s[k], wf3[k * 4 + t], a);
    out[t] = a;
  }
}

// ---------------------------------------------------------------------------
extern "C" void kernel_launch(void* const* d_in, const int* in_sizes, int n_in,
                              void* d_out, int out_size, void* d_ws, size_t ws_size,
                              hipStream_t stream) {
  (void)in_sizes; (void)n_in; (void)out_size; (void)ws_size;
  const float* glob_feature = (const float*)d_in[0];
  const float* roi          = (const float*)d_in[1];
  const float* bbox         = (const float*)d_in[2];
  const float* w_glob1      = (const float*)d_in[3];
  const float* b_glob1      = (const float*)d_in[4];
  const float* w_glob2      = (const float*)d_in[5];
  const float* b_glob2      = (const float*)d_in[6];
  const float* w_obj1       = (const float*)d_in[7];
  const float* b_obj1       = (const float*)d_in[8];
  const float* w_obj2       = (const float*)d_in[9];
  const float* b_obj2       = (const float*)d_in[10];
  const float* w_sel1       = (const float*)d_in[11];
  const float* b_sel1       = (const float*)d_in[12];
  const float* w_sel2       = (const float*)d_in[13];
  const float* b_sel2       = (const float*)d_in[14];
  const float* w_sel3       = (const float*)d_in[15];
  const float* b_sel3       = (const float*)d_in[16];
  const float* w_fc1        = (const float*)d_in[17];
  const float* b_fc1        = (const float*)d_in[18];
  const float* w_fc2        = (const float*)d_in[19];
  const float* b_fc2        = (const float*)d_in[20];
  const float* w_fc3        = (const float*)d_in[21];
  const float* b_fc3        = (const float*)d_in[22];

  float* ws = (float*)d_ws;
  _Float16* xh1     = (_Float16*)(ws);                 // [0, 12845056) floats
  _Float16* wbuf1   = (_Float16*)(ws + 12845056);      // 18,874,368 halves
  _Float16* obj1buf = (_Float16*)(ws + 22282240);      // [obj][49][1024] fp16
  // region [0, 12845056) reused after obj1:
  _Float16* sint    = (_Float16*)(ws);                 // [obj][49][544] fp16
  _Float16* wbuf2   = (_Float16*)(ws + 3411968);
  _Float16* wbufs1  = (_Float16*)(ws + 4591616);
  float*    sel1buf = ws + 5218304;
  float*    glob1buf= ws + 6856704;
  float*    part1   = ws + 6957056;
  float*    part2   = ws + 8562688;
  float*    sel2buf = ws + 8763392;
  float*    globbuf = ws + 8800256;

  // L1: obj1 weight transform + roi convert/transpose (fused)
  prep1<<<dim3(6144), 256, 0, stream>>>(w_obj1, wbuf1, roi, xh1);
  // L2: obj1 conv (473 GFLOP)
  conv_mfma2<2048, 512, 7, 7, 1, 2, 128>
      <<<dim3(256), 512, 0, stream>>>(wbuf1, xh1, b_obj1, obj1buf, 1024, 0);
  // L3: obj2/sel1 weight transforms + glob1 partial conv (fused; region A free)
  prep2<<<dim3(904), 256, 0, stream>>>(w_obj2, wbuf2, w_sel1, wbufs1,
                                       w_glob1, glob_feature, part1);
  // L4-L6: glob path
  reduce_bias_relu<<<dim3(392), 256, 0, stream>>>(part1, b_glob1, glob1buf, 100352, 196, 16);
  conv_gemm<256, 512, 4, 4, 14, 14, 7, 7, 2, 1, 1, 256, 0, true, 4, 4, 16, true>
      <<<dim3(1, 4, 16), 256, 0, stream>>>(w_glob2, glob1buf, b_glob2, part2);
  reduce_bias_relu<<<dim3(49), 256, 0, stream>>>(part2, b_glob2, globbuf, 12544, 49, 16);
  // L7: sin_t channels 0..3 / 260..543
  prep_sin_t<<<dim3(256), 256, 0, stream>>>(bbox, globbuf, sint);
  // L8: obj2 (writes sin_t ch 4..259)
  conv_mfma<1024, 128, 4, 7, 1, true, _Float16, 2, 128>
      <<<dim3(256), 512, 0, stream>>>(wbuf2, obj1buf, b_obj2, sint, 544, 4);
  // L9: sel1
  conv_mfma<544, 128, 2, 5, 0, false, float, 2, 128>
      <<<dim3(256), 512, 0, stream>>>(wbufs1, sint, b_sel1, sel1buf, 256, 0);
  // L10: sel2
  sel2_kernel<<<dim3(1024), 256, 0, stream>>>(sel1buf, w_sel2, b_sel2, sel2buf);
  // L11: scores + top5 + pool + fc head
  head_kernel<<<dim3(1), 512, 0, stream>>>(sel2buf, w_sel3, b_sel3, sint,
                                           globbuf, w_fc1, b_fc1, w_fc2, b_fc2,
                                           w_fc3, b_fc3, (float*)d_out);
}

// Round 10
// 956.684 us; speedup vs baseline: 1.0537x; 1.0537x over previous
//
#include <hip/hip_runtime.h>
#include <math.h>

using half8 = __attribute__((ext_vector_type(8))) _Float16;
using half4 = __attribute__((ext_vector_type(4))) _Float16;
using f32x4 = __attribute__((ext_vector_type(4))) float;

// ---------------------------------------------------------------------------
// Weight re-tiling (device): w (OIHW fp32) -> Wt fp16 tiles [mt][ktile][g][mi][8].
// ktile order: cc (ci chunks of 128) -> khkw (9) -> sub (cw/32).
// ---------------------------------------------------------------------------
template<int CIN, int KC, int M_, int BM>
__device__ void transform_w_dev(float* lds, const float* __restrict__ w,
                                _Float16* __restrict__ wt, int s, int m0, int tid) {
  constexpr int NT = (KC / 32) * 9;
  const int ci0 = s * 32;
  int vlen = (CIN - ci0) * 9;
  if (vlen > 288) vlen = 288;
  if (vlen < 0) vlen = 0;
  for (int e = tid; e < 32 * 288; e += 256) {
    const int mi = e / 288, o = e - mi * 288;
    float v = 0.f;
    if (o < vlen) v = w[(size_t)(m0 + mi) * (CIN * 9) + (size_t)ci0 * 9 + o];
    lds[mi * 289 + o] = v;
  }
  __syncthreads();
  const int cc = s >> 2, sub = s & 3;
  int ns = (KC - 128 * cc) / 32; if (ns > 4) ns = 4;
  const int mt = m0 / BM;
  const int mb = m0 - mt * BM;
  _Float16* base = wt + (size_t)mt * NT * (BM * 32);
  for (int u = tid; u < 36 * 256; u += 256) {
    const int chunk = u >> 8, within = u & 255;
    const int g = chunk & 3, khkw = chunk >> 2;
    const int mi = within >> 3, i = within & 7;
    const int kt = 36 * cc + khkw * ns + sub;
    const float v = lds[mi * 289 + (8 * g + i) * 9 + khkw];
    base[(size_t)kt * (BM * 32) + g * (BM * 8) + (mb + mi) * 8 + i] = (_Float16)v;
  }
}

// Convert + transpose roi chunk: fp32 (obj, 2048, 49) -> fp16 [obj][pos][ci].
__device__ void convert_tr_dev(_Float16 (*t_s)[136], const float* __restrict__ x,
                               _Float16* __restrict__ xh, int cb, int obj, int tid) {
  const int cbase = cb * 128;
  const float* src = x + (size_t)obj * 2048 * 49 + (size_t)cbase * 49;
  for (int e = tid; e < 128 * 49; e += 256) {
    const int ci = e / 49, pos = e - ci * 49;
    t_s[pos][ci] = (_Float16)src[e];
  }
  __syncthreads();
  _Float16* dst = xh + (size_t)obj * 49 * 2048 + cbase;
  for (int u = tid; u < 49 * 16; u += 256) {
    const int pos = u >> 4, l = u & 15;
    *(half8*)&dst[(size_t)pos * 2048 + l * 8] = *(const half8*)&t_s[pos][l * 8];
  }
}

// ---------------------------------------------------------------------------
// fp32 implicit-GEMM conv (device) + split-K partial output (glob path).
// ---------------------------------------------------------------------------
template<int M_, int CIN, int KH, int KW, int H, int W, int OH, int OW,
         int STRIDE, int PAD, int BATCH, int OUTC, int CO_OFF, bool RELU,
         int TM, int TN, int KSPLIT, bool PARTIAL>
__device__ void conv_gemm_dev(char* shraw, const float* __restrict__ A,
                              const float* __restrict__ X,
                              const float* __restrict__ bias,
                              float* __restrict__ out,
                              int n0, int m0, int kz, int t) {
  constexpr int K   = CIN * KH * KW;
  constexpr int N   = BATCH * OH * OW;
  constexpr int BK  = 16;
  constexpr int BM  = 16 * TM;
  constexpr int BN  = 16 * TN;
  constexpr int KCH = K / KSPLIT;

  float (*a_s)[BM] = (float (*)[BM])shraw;
  float (*b_s)[BN] = (float (*)[BN])(shraw + sizeof(float) * BK * BM);

  const int tx = t & 15;
  const int ty = t >> 4;
  constexpr int AQ    = TM / 4;
  constexpr int TPR_A = 4 / AQ;
  const int am = t / TPR_A;
  const int ak = (t % TPR_A) * (4 * AQ);
  constexpr int BQ = TN / 4;
  const int bk = t & 15;
  const int bn = (t >> 4) * TN;

  float acc[TM][TN];
#pragma unroll
  for (int i = 0; i < TM; i++)
#pragma unroll
    for (int j = 0; j < TN; j++) acc[i][j] = 0.f;

  for (int k0 = kz * KCH; k0 < (kz + 1) * KCH; k0 += BK) {
    float4 av[AQ];
#pragma unroll
    for (int q = 0; q < AQ; q++) {
      av[q] = make_float4(0.f, 0.f, 0.f, 0.f);
      const int kq = k0 + ak + 4 * q;
      if ((m0 + am) < M_ && kq < K)
        av[q] = *reinterpret_cast<const float4*>(&A[(m0 + am) * K + kq]);
    }
    float bv[TN];
#pragma unroll
    for (int q = 0; q < TN; q++) bv[q] = 0.f;
    {
      const int kk = k0 + bk;
      if (kk < K) {
        const int ci = kk / (KH * KW);
        const int r  = kk - ci * (KH * KW);
        const int kh = r / KW;
        const int kw = r - kh * KW;
#pragma unroll
        for (int q = 0; q < TN; q++) {
          const int n = n0 + bn + q;
          if (n < N) {
            const int b   = n / (OH * OW);
            const int pos = n - b * (OH * OW);
            const int oh  = pos / OW;
            const int ow  = pos - oh * OW;
            const int ih  = oh * STRIDE - PAD + kh;
            const int iw  = ow * STRIDE - PAD + kw;
            if (ih >= 0 && ih < H && iw >= 0 && iw < W)
              bv[q] = X[((b * CIN + ci) * H + ih) * W + iw];
          }
        }
      }
    }
    __syncthreads();
#pragma unroll
    for (int q = 0; q < AQ; q++) {
      const int kq = ak + 4 * q;
      a_s[kq + 0][am] = av[q].x;
      a_s[kq + 1][am] = av[q].y;
      a_s[kq + 2][am] = av[q].z;
      a_s[kq + 3][am] = av[q].w;
    }
#pragma unroll
    for (int q = 0; q < BQ; q++)
      *reinterpret_cast<float4*>(&b_s[bk][bn + 4 * q]) =
          make_float4(bv[4 * q], bv[4 * q + 1], bv[4 * q + 2], bv[4 * q + 3]);
    __syncthreads();
#pragma unroll
    for (int kk2 = 0; kk2 < BK; kk2++) {
      float a[TM], b[TN];
#pragma unroll
      for (int q = 0; q < AQ; q++)
        *reinterpret_cast<float4*>(&a[4 * q]) =
            *reinterpret_cast<const float4*>(&a_s[kk2][ty * TM + 4 * q]);
#pragma unroll
      for (int q = 0; q < BQ; q++)
        *reinterpret_cast<float4*>(&b[4 * q]) =
            *reinterpret_cast<const float4*>(&b_s[kk2][tx * TN + 4 * q]);
#pragma unroll
      for (int i = 0; i < TM; i++)
#pragma unroll
        for (int j = 0; j < TN; j++)
          acc[i][j] = fmaf(a[i], b[j], acc[i][j]);
    }
  }

#pragma unroll
  for (int i = 0; i < TM; i++) {
    const int m = m0 + ty * TM + i;
    if (m < M_) {
#pragma unroll
      for (int j = 0; j < TN; j++) {
        const int n = n0 + tx * TN + j;
        if (n < N) {
          if (PARTIAL) {
            out[((size_t)kz * M_ + m) * N + n] = acc[i][j];
          } else {
            float v = acc[i][j] + bias[m];
            if (RELU) v = fmaxf(v, 0.f);
            const int b   = n / (OH * OW);
            const int pos = n - b * (OH * OW);
            out[(b * OUTC + CO_OFF + m) * (OH * OW) + pos] = v;
          }
        }
      }
    }
  }
}

template<int M_, int CIN, int KH, int KW, int H, int W, int OH, int OW,
         int STRIDE, int PAD, int BATCH, int OUTC, int CO_OFF, bool RELU,
         int TM, int TN, int KSPLIT, bool PARTIAL>
__global__ __launch_bounds__(256)
void conv_gemm(const float* __restrict__ A, const float* __restrict__ X,
               const float* __restrict__ bias, float* __restrict__ out) {
  __shared__ char sh[16 * (16 * TM + 16 * TN) * 4];
  conv_gemm_dev<M_, CIN, KH, KW, H, W, OH, OW, STRIDE, PAD, BATCH, OUTC, CO_OFF,
                RELU, TM, TN, KSPLIT, PARTIAL>(
      sh, A, X, bias, out, blockIdx.x * 16 * TN, blockIdx.y * 16 * TM,
      blockIdx.z, threadIdx.x);
}

// ---------------------------------------------------------------------------
// Fused prep kernels (blockIdx dispatch).
// ---------------------------------------------------------------------------
__global__ __launch_bounds__(256)
void prep1(const float* __restrict__ w_obj1, _Float16* __restrict__ wbuf1,
           const float* __restrict__ roi, _Float16* __restrict__ xh1) {
  __shared__ char sh[32 * 289 * 4];
  int b = blockIdx.x;
  if (b < 2048) {
    transform_w_dev<2048, 2048, 1024, 256>((float*)sh, w_obj1, wbuf1,
                                           b & 63, (b >> 6) * 32, threadIdx.x);
  } else {
    b -= 2048;  // 4096 blocks
    convert_tr_dev((_Float16(*)[136])sh, roi, xh1, b & 15, b >> 4, threadIdx.x);
  }
}

__global__ __launch_bounds__(256)
void prep2(const float* __restrict__ w_obj2, _Float16* __restrict__ wbuf2,
           const float* __restrict__ w_sel1, _Float16* __restrict__ wbufs1,
           const float* __restrict__ w_glob1, const float* __restrict__ gfeat,
           float* __restrict__ part1) {
  __shared__ char sh[32 * 289 * 4];
  int b = blockIdx.x;
  if (b < 256) {
    transform_w_dev<1024, 1024, 256, 128>((float*)sh, w_obj2, wbuf2,
                                          b & 31, (b >> 5) * 32, threadIdx.x);
  } else if (b < 392) {
    b -= 256;  // 136 blocks
    transform_w_dev<516, 544, 256, 128>((float*)sh, w_sel1, wbufs1,
                                        b % 17, (b / 17) * 32, threadIdx.x);
  } else {
    b -= 392;  // 512 blocks
    conv_gemm_dev<512, 1024, 4, 4, 28, 28, 14, 14, 2, 1, 1, 512, 0, true,
                  4, 4, 16, true>(sh, w_glob1, gfeat, nullptr, part1,
                                  (b & 3) * 64, ((b >> 2) & 7) * 64, b >> 5,
                                  threadIdx.x);
  }
}

// ---------------------------------------------------------------------------
// Unified fp16 MFMA implicit-GEMM conv, 3x3 on 7x7 inputs (NCHW-transposed IO).
// NW waves; each wave owns WM=BM/NW channels (FR=WM/16), computes FN
// position-fragments covering OBJS objects. X staged per 128-ci chunk (raw
// barriers, loads in flight); weights reg-pipelined depth 2; setprio; XCD-
// aware decode. TOUT: LDS-transpose epilogue (aliases x_s).
// ---------------------------------------------------------------------------
template<int KC, int BM, int NW, int OBJS, int FN, int OHW, int PAD, bool TOUT,
         typename OUT_T, int NMT>
__global__ __launch_bounds__(NW * 64)
void conv_u(const _Float16* __restrict__ Wt, const _Float16* __restrict__ X,
            const float* __restrict__ bias, OUT_T* __restrict__ out,
            int outc, int co_off) {
  constexpr int NT    = (KC / 32) * 9;
  constexpr int OPOS  = OHW * OHW;
  constexpr int WM    = BM / NW;
  constexpr int FR    = WM / 16;
  constexpr int NTHR  = NW * 64;
  constexpr int CFULL = KC / 128;
  constexpr int TAIL  = KC - CFULL * 128;   // 0 or 32
  constexpr int NCH   = CFULL + (TAIL ? 1 : 0);
  constexpr int NOPB  = 256 / OBJS;         // op-blocks (objects or pairs)
  constexpr int NU    = OBJS * 49 * 16;     // half8 units per 128-chunk
  constexpr int NV    = (NU + NTHR - 1) / NTHR;
  constexpr int NUT   = OBJS * 49 * 4;      // units for 32-wide tail
  constexpr int NVT   = (NUT + NTHR - 1) / NTHR;

  __shared__ alignas(16) _Float16 x_s[OBJS][50][136];

  const int tid  = threadIdx.x;
  const int wid  = tid >> 6;
  const int lane = tid & 63;
  const int g    = lane >> 4;
  const int ln   = lane & 15;
  const int wm   = wid * WM;

  // XCD-aware decode: blockIdx%8 round-robins across XCDs; each XCD group
  // owns one mt weight tile.
  const int bid = blockIdx.x;
  const int j = bid & 7, q = bid >> 3;
  constexpr int OPJ = 8 / NMT;
  const int mt  = j / OPJ;
  const int opb = (j % OPJ) * (NOPB / OPJ) + q;

  // zero row (row 49) for padding/OOB -- STRIDE LOOP (R9 bug: with NTHR=256
  // and OBJS=2 a plain `if (tid < 272)` left 16 entries uninitialized).
  for (int e = tid; e < OBJS * 136; e += NTHR)
    x_s[e / 136][49][e % 136] = (_Float16)0.f;

  int ohv[FN], owv[FN], objv[FN];
  bool pvv[FN];
#pragma unroll
  for (int f = 0; f < FN; f++) {
    const int p = ln + 16 * f;
    pvv[f] = p < OBJS * OPOS;
    const int ob = pvv[f] ? (p / OPOS) : (OBJS - 1);
    objv[f] = ob;
    const int pp = pvv[f] ? (p - ob * OPOS) : 0;
    ohv[f] = pp / OHW;
    owv[f] = pp % OHW;
  }

  f32x4 acc[FR][FN];
#pragma unroll
  for (int r = 0; r < FR; r++)
#pragma unroll
    for (int f = 0; f < FN; f++) acc[r][f] = (f32x4){0.f, 0.f, 0.f, 0.f};

  const _Float16* Xh = X + (size_t)opb * OBJS * 49 * KC;

  half8 rg[NV];
  auto load_chunk = [&](int cbase, int cw) {
    if (cw == 128) {
#pragma unroll
      for (int v = 0; v < NV; v++) {
        const int u = v * NTHR + tid;
        if (u < NU) {
          const int row = u >> 4, l = u & 15;
          const int o = (row >= 49) ? 1 : 0, pos = row - 49 * o;
          rg[v] = *(const half8*)(Xh + (size_t)(o * 49 + pos) * KC + cbase + l * 8);
        }
      }
    } else {  // cw == 32
#pragma unroll
      for (int v = 0; v < NVT; v++) {
        const int u = v * NTHR + tid;
        if (u < NUT) {
          const int row = u >> 2, l = u & 3;
          const int o = (row >= 49) ? 1 : 0, pos = row - 49 * o;
          rg[v] = *(const half8*)(Xh + (size_t)(o * 49 + pos) * KC + cbase + l * 8);
        }
      }
    }
  };
  auto write_chunk = [&](int cw) {
    if (cw == 128) {
#pragma unroll
      for (int v = 0; v < NV; v++) {
        const int u = v * NTHR + tid;
        if (u < NU) {
          const int row = u >> 4, l = u & 15;
          const int o = (row >= 49) ? 1 : 0, pos = row - 49 * o;
          *(half8*)&x_s[o][pos][l * 8] = rg[v];
        }
      }
    } else {
#pragma unroll
      for (int v = 0; v < NVT; v++) {
        const int u = v * NTHR + tid;
        if (u < NUT) {
          const int row = u >> 2, l = u & 3;
          const int o = (row >= 49) ? 1 : 0, pos = row - 49 * o;
          *(half8*)&x_s[o][pos][l * 8] = rg[v];
        }
      }
    }
  };

  // weight register pipeline, depth 2 (3 rotating buffers); final prefetches
  // read <=2 ktiles past this mt tile -- valid ws memory, values unused.
  const _Float16* ap = Wt + (size_t)mt * NT * (BM * 32) + (g * BM + wm + ln) * 8;
  half8 afA[FR], afB[FR], afC[FR];
#pragma unroll
  for (int r = 0; r < FR; r++) afA[r] = *(const half8*)(ap + r * 128);
  ap += BM * 32;
#pragma unroll
  for (int r = 0; r < FR; r++) afB[r] = *(const half8*)(ap + r * 128);
  ap += BM * 32;

  load_chunk(0, KC < 128 ? KC : 128);

  auto kstep = [&](half8 (&cur)[FR], half8 (&fut)[FR], int subbyte,
                   const int (&boff)[FN]) {
#pragma unroll
    for (int r = 0; r < FR; r++) fut[r] = *(const half8*)(ap + r * 128);
    ap += BM * 32;
    __builtin_amdgcn_s_setprio(1);
    const char* xb = (const char*)(&x_s[0][0][0]) + subbyte;
#pragma unroll
    for (int f = 0; f < FN; f++) {
      const half8 bf = *(const half8*)(xb + boff[f]);
#pragma unroll
      for (int r = 0; r < FR; r++)
        acc[r][f] = __builtin_amdgcn_mfma_f32_16x16x32_f16(cur[r], bf, acc[r][f], 0, 0, 0);
    }
    __builtin_amdgcn_s_setprio(0);
  };

  for (int c = 0; c < NCH; c++) {
    const int cw = (c < CFULL) ? 128 : TAIL;
    asm volatile("s_barrier" ::: "memory");          // x_s reads of c-1 done
    write_chunk(cw);
    if (c + 1 < NCH) load_chunk((c + 1) * 128, (c + 1 < CFULL) ? 128 : TAIL);
    asm volatile("s_waitcnt lgkmcnt(0)\n\ts_barrier" ::: "memory");
    if (cw == 128) {
#pragma unroll
      for (int t9 = 0; t9 < 9; t9++) {
        const int kh = t9 / 3, kw = t9 - 3 * (t9 / 3);
        int boff[FN];
#pragma unroll
        for (int f = 0; f < FN; f++) {
          const int ih = ohv[f] + kh - PAD;
          const int iw = owv[f] + kw - PAD;
          bool v = pvv[f];
          if (PAD) v = v && ((unsigned)ih < 7u) && ((unsigned)iw < 7u);
          const int row = v ? (ih * 7 + iw) : 49;
          boff[f] = (objv[f] * 50 * 136 + row * 136) * 2;
        }
#pragma unroll
        for (int s4 = 0; s4 < 4; s4++) {
          const int ph = (t9 * 4 + s4) % 3;          // 36 % 3 == 0 per chunk
          const int subbyte = (s4 * 32 + 8 * g) * 2;
          if (ph == 0)      kstep(afA, afC, subbyte, boff);
          else if (ph == 1) kstep(afB, afA, subbyte, boff);
          else              kstep(afC, afB, subbyte, boff);
        }
      }
    } else {  // tail: cw==32, one sub per khkw, 9 ksteps (9 % 3 == 0)
#pragma unroll
      for (int t9 = 0; t9 < 9; t9++) {
        const int kh = t9 / 3, kw = t9 - 3 * (t9 / 3);
        int boff[FN];
#pragma unroll
        for (int f = 0; f < FN; f++) {
          const int ih = ohv[f] + kh - PAD;
          const int iw = owv[f] + kw - PAD;
          bool v = pvv[f];
          if (PAD) v = v && ((unsigned)ih < 7u) && ((unsigned)iw < 7u);
          const int row = v ? (ih * 7 + iw) : 49;
          boff[f] = (objv[f] * 50 * 136 + row * 136) * 2;
        }
        const int ph = t9 % 3;
        const int subbyte = (8 * g) * 2;
        if (ph == 0)      kstep(afA, afC, subbyte, boff);
        else if (ph == 1) kstep(afB, afA, subbyte, boff);
        else              kstep(afC, afB, subbyte, boff);
      }
    }
  }

  // ---- epilogue ----
  if constexpr (TOUT) {
    _Float16 (*ot_s)[49][132] = (_Float16 (*)[49][132]) & x_s[0][0][0];
    constexpr int PASSES = BM / 128;
#pragma unroll
    for (int p = 0; p < PASSES; p++) {
      asm volatile("s_waitcnt lgkmcnt(0)\n\ts_barrier" ::: "memory");
      if (wm >= 128 * p && wm < 128 * (p + 1)) {
#pragma unroll
        for (int f = 0; f < FN; f++) {
          if (pvv[f]) {
            const int pos = ohv[f] * OHW + owv[f];
            const int ob  = objv[f];
#pragma unroll
            for (int r = 0; r < FR; r++) {
              const int cl = wm - 128 * p + r * 16 + g * 4;
              half4 h;
#pragma unroll
              for (int e = 0; e < 4; e++)
                h[e] = (_Float16)fmaxf(
                    acc[r][f][e] + bias[mt * BM + wm + r * 16 + g * 4 + e], 0.f);
              *(half4*)&ot_s[ob][pos][cl] = h;
            }
          }
        }
      }
      asm volatile("s_waitcnt lgkmcnt(0)\n\ts_barrier" ::: "memory");
      for (int u = tid; u < OBJS * OPOS * 32; u += NTHR) {
        const int row = u >> 5, l = u & 31;
        const int o = (row >= OPOS) ? 1 : 0, pos = row - OPOS * o;
        const half4 v = *(const half4*)&ot_s[o][pos][l * 4];
        *(half4*)&((_Float16*)out)[((size_t)(opb * OBJS + o) * OPOS + pos) * outc +
                                   co_off + mt * BM + 128 * p + l * 4] = v;
      }
    }
  } else {
#pragma unroll
    for (int f = 0; f < FN; f++) {
      if (pvv[f]) {
        const int pos = ohv[f] * OHW + owv[f];
        const int bo  = opb * OBJS + objv[f];
#pragma unroll
        for (int r = 0; r < FR; r++) {
          const int mrow = mt * BM + wm + r * 16 + g * 4;
#pragma unroll
          for (int e = 0; e < 4; e++) {
            const int m = mrow + e;
            float v = fmaxf(acc[r][f][e] + bias[m], 0.f);
            out[((size_t)bo * outc + co_off + m) * OPOS + pos] = (OUT_T)v;
          }
        }
      }
    }
  }
}

__global__ void reduce_bias_relu(const float* __restrict__ part,
                                 const float* __restrict__ bias,
                                 float* __restrict__ out, int MN, int N, int KS) {
  const int e = blockIdx.x * 256 + threadIdx.x;
  if (e >= MN) return;
  float s = 0.f;
  for (int k = 0; k < KS; k++) s += part[(size_t)k * MN + e];
  s += bias[e / N];
  out[e] = fmaxf(s, 0.f);
}

// sel2: x = sel1buf f32 (256,256,5,5) NCHW, w (16,256,3,3) -> out (256,16,9).
__global__ __launch_bounds__(256)
void sel2_kernel(const float* __restrict__ x, const float* __restrict__ w,
                 const float* __restrict__ b, float* __restrict__ out) {
  const int wv   = (blockIdx.x * 256 + threadIdx.x) >> 6;
  const int lane = threadIdx.x & 63;
  const int obj  = wv >> 4, co = wv & 15;
  float acc[9];
#pragma unroll
  for (int p = 0; p < 9; p++) acc[p] = 0.f;
  const float* xo = x + (size_t)obj * 256 * 25;
  const float* wo = w + (size_t)co * 2304;
  for (int k = lane; k < 2304; k += 64) {
    const int ci = k / 9, rr = k - 9 * ci;
    const int kh = rr / 3, kw = rr - 3 * kh;
    const float wval = wo[k];
    const float* xc = xo + ci * 25;
#pragma unroll
    for (int oh = 0; oh < 3; oh++)
#pragma unroll
      for (int ow = 0; ow < 3; ow++)
        acc[oh * 3 + ow] = fmaf(xc[(oh + kh) * 5 + (ow + kw)], wval, acc[oh * 3 + ow]);
  }
  const float bv = b[co];
#pragma unroll
  for (int p = 0; p < 9; p++) {
    float v = acc[p];
#pragma unroll
    for (int off = 32; off; off >>= 1) v += __shfl_xor(v, off);
    if (lane == 0) out[(size_t)wv * 9 + p] = fmaxf(v + bv, 0.f);
  }
}

// sin_t buffer (256, 49, 544) fp16: ch 0..3 = bb, 260..515 = glob, 516..543=0.
__global__ void prep_sin_t(const float* __restrict__ bbox,
                           const float* __restrict__ glob,
                           _Float16* __restrict__ sint) {
  const int b = blockIdx.x;
  const float x0 = bbox[b * 4 + 0], y0 = bbox[b * 4 + 1];
  const float x1 = bbox[b * 4 + 2], y1 = bbox[b * 4 + 3];
  const float bbv[4] = {x0 / 1280.f, y0 / 720.f,
                        logf(1280.f / (x1 - x0)), logf(720.f / (y1 - y0))};
  _Float16* base = sint + (size_t)b * 49 * 544;
  for (int e = threadIdx.x; e < 49 * 288; e += blockDim.x) {
    const int pos = e / 288, q = e - pos * 288;
    float v; int c;
    if (q < 4)        { v = bbv[q];                   c = q; }
    else if (q < 260) { v = glob[(q - 4) * 49 + pos]; c = q + 256; }
    else              { v = 0.f;                      c = q + 256; }
    base[pos * 544 + c] = (_Float16)v;
  }
}

// ---------------------------------------------------------------------------
// head: scores (sel3) + stable top-5 + pooling + fc1 + fc2 + fc3, one block.
// ---------------------------------------------------------------------------
__global__ __launch_bounds__(512)
void head_kernel(const float* __restrict__ sel2, const float* __restrict__ w3,
                 const float* __restrict__ b3, const _Float16* __restrict__ sint,
                 const float* __restrict__ glob, const float* __restrict__ w1,
                 const float* __restrict__ b1, const float* __restrict__ w2,
                 const float* __restrict__ b2, const float* __restrict__ wf3,
                 const float* __restrict__ bf3, float* __restrict__ out) {
  __shared__ float w3_s[144];
  __shared__ float s_s[256];
  __shared__ int   idx_s[5];
  __shared__ float objsel_s[5 * 260];
  __shared__ float g_s[256];
  __shared__ float x1_s[1280];
  __shared__ float x2_s[64];
  const int t = threadIdx.x;
  if (t < 144) w3_s[t] = w3[t];
  __syncthreads();
  if (t < 256) {
    float acc = b3[0];
    const float* p = sel2 + t * 144;
    for (int k = 0; k < 144; k++) acc += p[k] * w3_s[k];
    s_s[t] = acc;
  } else {
    const int c = t - 256;
    float s = 0.f;
    const float* p = glob + c * 49;
    for (int q = 0; q < 49; q++) s += p[q];
    g_s[c] = s * (1.f / 49.f);
  }
  __syncthreads();
  if (t == 0) {
    // argsort(-s) stable: strict '>' + ascending scan = smallest index first
    for (int i = 0; i < 5; i++) {
      float best = -1e30f; int bi = 0;
      for (int j = 0; j < 256; j++)
        if (s_s[j] > best) { best = s_s[j]; bi = j; }
      idx_s[i] = bi;
      s_s[bi] = -1e30f;
    }
  }
  __syncthreads();
  for (int e = t; e < 5 * 260; e += 512) {
    const int i = e / 260, c = e - 260 * i;
    const _Float16* base = sint + (size_t)idx_s[i] * 49 * 544;
    float s = 0.f;
    for (int p = 0; p < 49; p++) s += (float)base[p * 544 + c];
    objsel_s[e] = s * (1.f / 245.f);
  }
  __syncthreads();
  if (t < 256) {
    float acc[5];
#pragma unroll
    for (int i = 0; i < 5; i++) acc[i] = b1[t];
    for (int k = 0; k < 260; k++) {
      const float wv = w1[k * 256 + t];
#pragma unroll
      for (int i = 0; i < 5; i++) acc[i] = fmaf(objsel_s[i * 260 + k], wv, acc[i]);
    }
    for (int k = 260; k < 516; k++) {
      const float wv = w1[k * 256 + t];
      const float gv = g_s[k - 260];
#pragma unroll
      for (int i = 0; i < 5; i++) acc[i] = fmaf(gv, wv, acc[i]);
    }
#pragma unroll
    for (int i = 0; i < 5; i++) x1_s[i * 256 + t] = fmaxf(acc[i], 0.f);
  }
  __syncthreads();
  if (t < 64) {
    float a = b2[t];
    for (int k = 0; k < 1280; k++) a = fmaf(x1_s[k], w2[k * 64 + t], a);
    x2_s[t] = fmaxf(a, 0.f);
  }
  __syncthreads();
  if (t < 4) {
    float a = bf3[t];
    for (int k = 0; k < 64; k++) a = fmaf(x2_s[k], wf3[k * 4 + t], a);
    out[t] = a;
  }
}

// ---------------------------------------------------------------------------
extern "C" void kernel_launch(void* const* d_in, const int* in_sizes, int n_in,
                              void* d_out, int out_size, void* d_ws, size_t ws_size,
                              hipStream_t stream) {
  (void)in_sizes; (void)n_in; (void)out_size; (void)ws_size;
  const float* glob_feature = (const float*)d_in[0];
  const float* roi          = (const float*)d_in[1];
  const float* bbox         = (const float*)d_in[2];
  const float* w_glob1      = (const float*)d_in[3];
  const float* b_glob1      = (const float*)d_in[4];
  const float* w_glob2      = (const float*)d_in[5];
  const float* b_glob2      = (const float*)d_in[6];
  const float* w_obj1       = (const float*)d_in[7];
  const float* b_obj1       = (const float*)d_in[8];
  const float* w_obj2       = (const float*)d_in[9];
  const float* b_obj2       = (const float*)d_in[10];
  const float* w_sel1       = (const float*)d_in[11];
  const float* b_sel1       = (const float*)d_in[12];
  const float* w_sel2       = (const float*)d_in[13];
  const float* b_sel2       = (const float*)d_in[14];
  const float* w_sel3       = (const float*)d_in[15];
  const float* b_sel3       = (const float*)d_in[16];
  const float* w_fc1        = (const float*)d_in[17];
  const float* b_fc1        = (const float*)d_in[18];
  const float* w_fc2        = (const float*)d_in[19];
  const float* b_fc2        = (const float*)d_in[20];
  const float* w_fc3        = (const float*)d_in[21];
  const float* b_fc3        = (const float*)d_in[22];

  float* ws = (float*)d_ws;
  _Float16* xh1     = (_Float16*)(ws);                 // [0, 12845056) floats
  _Float16* wbuf1   = (_Float16*)(ws + 12845056);      // 18,874,368 halves
  _Float16* obj1buf = (_Float16*)(ws + 22282240);      // [obj][49][1024] fp16
  // region [0, 12845056) reused after obj1:
  _Float16* sint    = (_Float16*)(ws);                 // [obj][49][544] fp16
  _Float16* wbuf2   = (_Float16*)(ws + 3411968);
  _Float16* wbufs1  = (_Float16*)(ws + 4591616);
  float*    sel1buf = ws + 5218304;
  float*    glob1buf= ws + 6856704;
  float*    part1   = ws + 6957056;
  float*    part2   = ws + 8562688;
  float*    sel2buf = ws + 8763392;
  float*    globbuf = ws + 8800256;

  // L1: obj1 weight transform (BM=256 tiles) + roi convert/transpose (fused)
  prep1<<<dim3(6144), 256, 0, stream>>>(w_obj1, wbuf1, roi, xh1);
  // L2: obj1 conv -- 512 blocks x 4 waves (2 independent blocks/CU), FN=7
  conv_u<2048, 256, 4, 2, 7, 7, 1, true, _Float16, 4>
      <<<dim3(512), 256, 0, stream>>>(wbuf1, xh1, b_obj1, obj1buf, 1024, 0);
  // L3: obj2/sel1 weight transforms + glob1 partial conv (fused)
  prep2<<<dim3(904), 256, 0, stream>>>(w_obj2, wbuf2, w_sel1, wbufs1,
                                       w_glob1, glob_feature, part1);
  // L4-L6: glob path
  reduce_bias_relu<<<dim3(392), 256, 0, stream>>>(part1, b_glob1, glob1buf, 100352, 196, 16);
  conv_gemm<256, 512, 4, 4, 14, 14, 7, 7, 2, 1, 1, 256, 0, true, 4, 4, 16, true>
      <<<dim3(1, 4, 16), 256, 0, stream>>>(w_glob2, glob1buf, b_glob2, part2);
  reduce_bias_relu<<<dim3(49), 256, 0, stream>>>(part2, b_glob2, globbuf, 12544, 49, 16);
  // L7: sin_t channels 0..3 / 260..543
  prep_sin_t<<<dim3(256), 256, 0, stream>>>(bbox, globbuf, sint);
  // L8: obj2 -- one object/block, 512 blocks x 4 waves, writes sin_t ch 4..259
  conv_u<1024, 128, 4, 1, 4, 7, 1, true, _Float16, 2>
      <<<dim3(512), 256, 0, stream>>>(wbuf2, obj1buf, b_obj2, sint, 544, 4);
  // L9: sel1 -- one object/block, 512 blocks x 4 waves
  conv_u<544, 128, 4, 1, 2, 5, 0, false, float, 2>
      <<<dim3(512), 256, 0, stream>>>(wbufs1, sint, b_sel1, sel1buf, 256, 0);
  // L10: sel2
  sel2_kernel<<<dim3(1024), 256, 0, stream>>>(sel1buf, w_sel2, b_sel2, sel2buf);
  // L11: scores + top5 + pool + fc head
  head_kernel<<<dim3(1), 512, 0, stream>>>(sel2buf, w_sel3, b_sel3, sint,
                                           globbuf, w_fc1, b_fc1, w_fc2, b_fc2,
                                           w_fc3, b_fc3, (float*)d_out);
}